// Round 1
// baseline (85.394 us; speedup 1.0000x reference)
//
#include <hip/hip_runtime.h>
#include <math.h>

// TopologicalValuePolicy — MI355X, R9: 4 waves per board (block = 1 board).
// R8 (wave-per-board, 0 barriers) sat at ~41us kernel vs ~6-8us issue math,
// insensitive to work cuts AND barrier cuts -> latency-bound at 4 waves/SIMD
// (grid-capped 16 waves/CU). This round: block(256)=1 board, grid=4096 ->
// 24-32 waves/CU (launch_bounds(256,6) caps VGPR at 85; LDS 8.3KB/block),
// per-wave serial path cut 5 position-bodies -> 1-1.5, staging depth 17 -> 5
// block-wide iterations. 3 __syncthreads total (stage + 2 softmax phases).
// Math identical to R8: e0 = l0-5(l1+l2), e1 = l1-5(l0+l2);
// a_v = (5-window sum of e_v) - 6*C_v; windows slid in registers.

__device__ __forceinline__ float fpow(float x, float e) {
    float r = __builtin_amdgcn_exp2f(e * __builtin_amdgcn_logf(x));
    return (x > 0.f) ? r : 0.f;
}
__device__ __forceinline__ float fexp(float x) {
    return __builtin_amdgcn_exp2f(x * 1.44269504088896f);
}

#define SLAB 1024          // float2 per board: 729 E + 289 C + pad
#define C_OFF 729

__device__ __forceinline__ float2 eval_pos(const float2* __restrict__ s2, int p)
{
    int y = p / 17, x = p - y * 17;
    float2 h = s2[C_OFF + p];
    // orientation line starts (i=0) and steps in the padded 27x27 plane
    int c0 = (y + 5) * 27 + (x + 1);   // H, step 1
    int c1 = (y + 1) * 27 + (x + 5);   // V, step 27
    int c2 = (y + 1) * 27 + (x + 1);   // D, step 28
    int c3 = (y + 1) * 27 + (x + 9);   // A, step 26
    float sd0 = 0.f, sd1 = 0.f;
    #define ORIENT(BASE, STEP)                                      \
    {                                                               \
        float2 e[9];                                                \
        _Pragma("unroll")                                           \
        for (int i = 0; i < 9; ++i) e[i] = s2[(BASE) + i * (STEP)]; \
        float wx = e[4].x + e[5].x + e[6].x + e[7].x + e[8].x;      \
        float wy = e[4].y + e[5].y + e[6].y + e[7].y + e[8].y;      \
        float t0 = 0.f, t1 = 0.f;                                   \
        _Pragma("unroll")                                           \
        for (int pp = 0; pp < 5; ++pp) {                            \
            float a0 = fmaxf(wx - h.x, 0.f);                        \
            float a1 = fmaxf(wy - h.y, 0.f);                        \
            float q0 = a0 * a0, q1 = a1 * a1;                       \
            t0 = fmaf(q0 * q0, q0, t0);                             \
            t1 = fmaf(q1 * q1, q1, t1);                             \
            if (pp < 4) {                                           \
                wx += e[3 - pp].x - e[8 - pp].x;                    \
                wy += e[3 - pp].y - e[8 - pp].y;                    \
            }                                                       \
        }                                                           \
        sd0 += fpow(t0, 5.0f / 6.0f);                               \
        sd1 += fpow(t1, 5.0f / 6.0f);                               \
    }
    ORIENT(c0, 1)
    ORIENT(c1, 27)
    ORIENT(c2, 28)
    ORIENT(c3, 26)
    #undef ORIENT
    return make_float2(fpow(sd0, 0.2f), fpow(sd1, 0.2f));
}

__global__ __launch_bounds__(256, 6) void topo_policy_value(
    const float* __restrict__ state,
    float* __restrict__ probs,
    float* __restrict__ value,
    int nb)
{
    __shared__ float2 s2[SLAB];
    __shared__ float red[4][3];   // [wave][M | S | dif]

    const int tid  = threadIdx.x;
    const int wv   = tid >> 6;           // wave in block 0..3
    const int lane = tid & 63;
    const int b    = blockIdx.x;         // one board per block; grid == nb

    const float* src = state + (size_t)b * (19 * 19 * 3);

    // ---- stage E plane (zero-padded 27x27), block-wide: 3 iters ----
    #pragma unroll
    for (int it = 0; it < 3; ++it) {
        int j = tid + it * 256;
        if (j < 729) {
            int py = j / 27, px = j - py * 27;
            int r = py - 4, c = px - 4;
            float l0 = 0.f, l1 = 0.f, lv = 0.f;
            if ((unsigned)r < 19u && (unsigned)c < 19u) {
                int o = 3 * (r * 19 + c);
                l0 = src[o]; l1 = src[o + 1]; lv = src[o + 2];
            }
            s2[j] = make_float2(fmaf(-5.f, l1 + lv, l0),
                                fmaf(-5.f, l0 + lv, l1));
        }
    }
    // ---- stage center pairs (6*l0, 6*l1), block-wide: 2 iters ----
    #pragma unroll
    for (int it = 0; it < 2; ++it) {
        int j = tid + it * 256;
        if (j < 289) {
            int y = j / 17, x = j - y * 17;
            int o = 3 * ((y + 1) * 19 + (x + 1));
            s2[C_OFF + j] = make_float2(6.f * src[o], 6.f * src[o + 1]);
        }
    }
    __syncthreads();

    // ---- positions: every thread owns p = tid (0..255);
    //      wave 3 lanes 0..32 additionally own p = 256+lane ----
    float dif = 0.f;
    float gA, gB = -3.0e38f;
    {
        float2 r = eval_pos(s2, tid);
        gA = 2.f * (r.x + r.y);
        dif += r.x - r.y;
    }
    const bool hasB = (wv == 3) && (lane < 33);
    if (hasB) {
        float2 r = eval_pos(s2, 256 + lane);
        gB = 2.f * (r.x + r.y);
        dif += r.x - r.y;
    }

    // ---- softmax max: wave butterfly + 4-slot LDS combine ----
    float Mw = fmaxf(gA, gB);
    #pragma unroll
    for (int off = 32; off > 0; off >>= 1)
        Mw = fmaxf(Mw, __shfl_xor(Mw, off, 64));
    if (lane == 0) red[wv][0] = Mw;
    __syncthreads();
    const float M = fmaxf(fmaxf(red[0][0], red[1][0]),
                          fmaxf(red[2][0], red[3][0]));

    // ---- exp + sum + dif: wave butterflies + 4-slot LDS combine ----
    float esA = fexp(gA - M);
    float esB = hasB ? fexp(gB - M) : 0.f;
    float Sw = esA + esB;
    #pragma unroll
    for (int off = 32; off > 0; off >>= 1) Sw += __shfl_xor(Sw, off, 64);
    #pragma unroll
    for (int off = 32; off > 0; off >>= 1) dif += __shfl_xor(dif, off, 64);
    if (lane == 0) { red[wv][1] = Sw; red[wv][2] = dif; }
    __syncthreads();
    const float S = (red[0][1] + red[1][1]) + (red[2][1] + red[3][1]);

    const float invS = __builtin_amdgcn_rcpf(S);
    float* pout = probs + (size_t)b * 289;
    pout[tid] = esA * invS;
    if (hasB) pout[256 + lane] = esB * invS;
    if (tid == 0) {
        float df = (red[0][2] + red[1][2]) + (red[2][2] + red[3][2]);
        float z = df * (0.2f / 32.0f);
        float t = __builtin_amdgcn_exp2f(z * (2.0f * 1.44269504088896f));
        value[b] = (t - 1.f) * __builtin_amdgcn_rcpf(t + 1.f);  // tanh(z)
    }
}

extern "C" void kernel_launch(void* const* d_in, const int* in_sizes, int n_in,
                              void* d_out, int out_size, void* d_ws, size_t ws_size,
                              hipStream_t stream) {
    const float* state = (const float*)d_in[0];
    const int nb = in_sizes[0] / (19 * 19 * 3);   // 4096
    float* probs = (float*)d_out;                  // (nb, 289)
    float* value = probs + (size_t)nb * 289;       // (nb,)
    topo_policy_value<<<dim3(nb), dim3(256), 0, stream>>>(state, probs, value, nb);
}